// Round 1
// 238.279 us; speedup vs baseline: 1.0764x; 1.0764x over previous
//
#include <hip/hip_runtime.h>
#include <cstdint>
#include <math.h>

// ---------------------------------------------------------------------------
// CausalSelfAttention (B=4, T=2048, D=1024, H=16, Dh=64), fp32 in/out,
// bf16 MFMA compute internally.
// Pipeline: fused cast -> fused QKV GEMM (256x128 tile, BK=64, counted-vmcnt
//           depth-2 prefetch, XOR-swizzled LDS, setprio MFMA clusters,
//           768 blocks = 3 exact CU rounds, V transposed in epilogue)
//           -> flash attention (unchanged) -> output projection (same GEMM,
//           256 blocks = 1 exact round, fp32 out).
// ---------------------------------------------------------------------------

typedef unsigned short u16;
typedef __bf16 bf16x8 __attribute__((ext_vector_type(8)));
typedef __bf16 bf16x4 __attribute__((ext_vector_type(4)));
typedef float f32x4 __attribute__((ext_vector_type(4)));

__device__ __forceinline__ u16 f32_bf16(float f) {  // round-nearest-even
  union { float f; uint32_t u; } c; c.f = f;
  uint32_t u = c.u;
  return (u16)((u + 0x7FFFu + ((u >> 16) & 1u)) >> 16);
}

__device__ __forceinline__ f32x4 mfma16(bf16x8 a, bf16x8 b, f32x4 c) {
  return __builtin_amdgcn_mfma_f32_16x16x32_bf16(a, b, c, 0, 0, 0);
}

// async global->LDS, 16B/lane. LDS dest must be wave-uniform base + lane*16.
__device__ __forceinline__ void gload_lds16(const u16* g, u16* l) {
  __builtin_amdgcn_global_load_lds(
      (const __attribute__((address_space(1))) void*)g,
      (__attribute__((address_space(3))) void*)l, 16, 0, 0);
}

// barrier that does NOT drain the newest 2 vm loads (attn t+2 prefetch)
__device__ __forceinline__ void barrier_vm2() {
  asm volatile("s_waitcnt vmcnt(2)\n\ts_barrier" ::: "memory");
}

// ---------------------------------------------------------------------------
// fused cast fp32->bf16 of x + 4 weights into contiguous ws region
// ---------------------------------------------------------------------------
__global__ __launch_bounds__(256) void cvt_all_kernel(
    const float* __restrict__ x,
    const float* __restrict__ wq, const float* __restrict__ wk,
    const float* __restrict__ wv, const float* __restrict__ wo,
    u16* __restrict__ dst, int n_x, int n_w) {
  int i = blockIdx.x * 256 + threadIdx.x;
  const float* src;
  int off;
  if (i < n_x) { src = x; off = i; }
  else {
    int j = i - n_x;
    int w = j / n_w;  off = j - w * n_w;
    src = (w == 0) ? wq : (w == 1) ? wk : (w == 2) ? wv : wo;
  }
  float4 f = ((const float4*)src)[off];
  ushort4 o;
  o.x = f32_bf16(f.x); o.y = f32_bf16(f.y);
  o.z = f32_bf16(f.z); o.w = f32_bf16(f.w);
  ((ushort4*)dst)[i] = o;
}

// ---------------------------------------------------------------------------
// 256x128-tile GEMM: C[m,n] = scale * sum_k A[m,k]*B[n,k] (both K-contiguous).
// BK=64, 512 threads = 8 waves (2M x 4N), per-wave 128x32 output.
// LDS 96 KiB: As[2][256*64], Bs[2][128*64] bf16, double-buffered.
//
// Schedule (T3/T4 counted vmcnt, prefetch depth 2):
//   per K-tile t (buffer c = t&1):
//     phase 1: 20 ds_read_b128 -> all A/B fragments of tile t into regs
//     lgkmcnt(0); s_barrier         (all waves done reading buf c)
//     4 MFMA clusters (8 mfma each, setprio-wrapped), the 6 global_load_lds
//       staging K-tile t+2 into buf c interleaved between clusters
//     vmcnt(6); s_barrier           (tile t+1 landed; t+2 stays in flight)
//   Tail (last 2 tiles): no staging, vmcnt(0) once.
//
// LDS swizzle (T2): byte ^= (row&7)<<4, as pre-swizzled GLOBAL source for the
// linear global_load_lds dest + swizzled ds_read offsets. Read pattern
// (quad^(l15&3), kh^((l15>>2)&1)) puts exactly 8 lanes on each 16B bank
// group -> conflict-free ds_read_b128 (was 6.3M conflict cycles/dispatch).
//
// MODE 0: fused QKV. N-space 3072 = 24 col-tiles; z = ct>>3 picks Q/K/V;
//         Q scaled by log2e/8; V written transposed Vt[(b*16+h)*64+d][t].
//         Grid 768 = 3 exact rounds of 256 CUs, XCD-bijective swizzle
//         (96 tiles/XCD = 4 row-strips x 24 col-tiles; 2MB A-slice L2-res).
// MODE 1: output projection, fp32 out, N=1024. Grid 256 = 1 exact round.
// ---------------------------------------------------------------------------
template <bool STG, int ENDW>  // ENDW: 6=vmcnt(6), 0=vmcnt(0), -1=none
__device__ __forceinline__ void kiter256(
    f32x4 (&acc)[8][2],
    const u16* __restrict__ AsP, const u16* __restrict__ BsP,
    u16* sA, u16* sB, const u16* gaK, const u16* gbK, int tid,
    int aoff0, int aoff1, int boff0, int boff1) {
  bf16x8 af[8][2], bf[2][2];
#pragma unroll
  for (int m = 0; m < 8; ++m) {
    af[m][0] = *(const bf16x8*)(AsP + aoff0 + m * 1024);
    af[m][1] = *(const bf16x8*)(AsP + aoff1 + m * 1024);
  }
#pragma unroll
  for (int n = 0; n < 2; ++n) {
    bf[n][0] = *(const bf16x8*)(BsP + boff0 + n * 1024);
    bf[n][1] = *(const bf16x8*)(BsP + boff1 + n * 1024);
  }
  // every wave's reads of this buffer complete before any re-stage can land
  asm volatile("s_waitcnt lgkmcnt(0)\n\ts_barrier" ::: "memory");
  if (STG) {
    gload_lds16(gaK, sA + tid * 8);
    gload_lds16(gaK + 65536, sA + 4096 + tid * 8);
  }
  __builtin_amdgcn_s_setprio(1);
#pragma unroll
  for (int m = 0; m < 4; ++m) {
    acc[m][0] = mfma16(af[m][0], bf[0][0], acc[m][0]);
    acc[m][0] = mfma16(af[m][1], bf[0][1], acc[m][0]);
  }
  __builtin_amdgcn_s_setprio(0);
  if (STG) {
    gload_lds16(gaK + 2 * 65536, sA + 2 * 4096 + tid * 8);
    gload_lds16(gaK + 3 * 65536, sA + 3 * 4096 + tid * 8);
  }
  __builtin_amdgcn_s_setprio(1);
#pragma unroll
  for (int m = 0; m < 4; ++m) {
    acc[m][1] = mfma16(af[m][0], bf[1][0], acc[m][1]);
    acc[m][1] = mfma16(af[m][1], bf[1][1], acc[m][1]);
  }
  __builtin_amdgcn_s_setprio(0);
  if (STG) gload_lds16(gbK, sB + tid * 8);
  __builtin_amdgcn_s_setprio(1);
#pragma unroll
  for (int m = 4; m < 8; ++m) {
    acc[m][0] = mfma16(af[m][0], bf[0][0], acc[m][0]);
    acc[m][0] = mfma16(af[m][1], bf[0][1], acc[m][0]);
  }
  __builtin_amdgcn_s_setprio(0);
  if (STG) gload_lds16(gbK + 65536, sB + 4096 + tid * 8);
  __builtin_amdgcn_s_setprio(1);
#pragma unroll
  for (int m = 4; m < 8; ++m) {
    acc[m][1] = mfma16(af[m][0], bf[1][0], acc[m][1]);
    acc[m][1] = mfma16(af[m][1], bf[1][1], acc[m][1]);
  }
  __builtin_amdgcn_s_setprio(0);
  if (ENDW == 6)
    asm volatile("s_waitcnt vmcnt(6)\n\ts_barrier" ::: "memory");
  else if (ENDW == 0)
    asm volatile("s_waitcnt vmcnt(0)\n\ts_barrier" ::: "memory");
}

template <int MODE>  // 0 = QKV (bf16 out, V transposed), 1 = proj (fp32 out)
__global__ __launch_bounds__(512, 2) void gemm256(
    const u16* __restrict__ A,
    const u16* __restrict__ B0, const u16* __restrict__ B1,
    const u16* __restrict__ B2,
    void* __restrict__ C0, void* __restrict__ C1, void* __restrict__ C2,
    float qscale) {
  constexpr int K = 1024;
  __shared__ u16 As[2][16384];  // [dbuf][256 rows x 64 k]
  __shared__ u16 Bs[2][8192];   // [dbuf][128 rows x 64 k]

  const int ord = blockIdx.x;
  const int xcd = ord & 7, g = ord >> 3;
  constexpr int NCT = (MODE == 0) ? 24 : 8;
  const int ct = g % NCT, rt = xcd * 4 + g / NCT;
  const int z = (MODE == 0) ? (ct >> 3) : 0;
  const int colm = (MODE == 0) ? (ct & 7) * 128 : ct * 128;
  const int row0 = rt * 256;
  const u16* Bv = (z == 0) ? B0 : (z == 1) ? B1 : B2;

  const int tid = threadIdx.x;
  const int lane = tid & 63, wid = tid >> 6;
  const int quad = lane >> 4, l15 = lane & 15;
  const int wm = wid >> 2, wn = wid & 3;

  // staging: linear LDS dest (ld*8192B + tid*16B), pre-swizzled global source
  //   dst row = ld*64 + tid/8, src chunk = (tid&7) ^ ((tid/8)&7)
  const int srow = tid >> 3;
  const int selem = ((tid & 7) ^ (srow & 7)) * 8;
  const u16* ga = A + (size_t)(row0 + srow) * K + selem;   // + ld*65536 + kt*64
  const u16* gb = Bv + (size_t)(colm + srow) * K + selem;  // + ld*65536 + kt*64

  u16* pA0 = &As[0][0];
  u16* pA1 = &As[1][0];
  u16* pB0 = &Bs[0][0];
  u16* pB1 = &Bs[1][0];

  // swizzled fragment read offsets (elements): chunk = (4kh+quad) ^ (l15&7)
  const int swz = 8 * (quad ^ (l15 & 3));
  const int kof = 32 * ((l15 >> 2) & 1);
  const int aoff0 = (wm * 128 + l15) * 64 + swz + kof;
  const int aoff1 = (wm * 128 + l15) * 64 + swz + (32 - kof);
  const int boff0 = (wn * 32 + l15) * 64 + swz + kof;
  const int boff1 = (wn * 32 + l15) * 64 + swz + (32 - kof);

  f32x4 acc[8][2];
  const f32x4 zero = {0.f, 0.f, 0.f, 0.f};
#pragma unroll
  for (int m = 0; m < 8; ++m) { acc[m][0] = zero; acc[m][1] = zero; }

  // prologue: stage K-tiles 0 and 1 (6 loads each, order A0..A3,B0,B1)
#pragma unroll
  for (int ld = 0; ld < 4; ++ld)
    gload_lds16(ga + ld * 65536, pA0 + ld * 4096 + tid * 8);
  gload_lds16(gb, pB0 + tid * 8);
  gload_lds16(gb + 65536, pB0 + 4096 + tid * 8);
#pragma unroll
  for (int ld = 0; ld < 4; ++ld)
    gload_lds16(ga + 64 + ld * 65536, pA1 + ld * 4096 + tid * 8);
  gload_lds16(gb + 64, pB1 + tid * 8);
  gload_lds16(gb + 64 + 65536, pB1 + 4096 + tid * 8);
  asm volatile("s_waitcnt vmcnt(6)\n\ts_barrier" ::: "memory");

  // main loop: K-tiles 0..13 (pairs), staging t+2; tail: 14,15 no staging
  for (int tp = 0; tp < 7; ++tp) {
    const int k2 = (tp * 2 + 2) * 64;
    kiter256<true, 6>(acc, pA0, pB0, pA0, pB0, ga + k2, gb + k2, tid,
                      aoff0, aoff1, boff0, boff1);
    kiter256<true, 6>(acc, pA1, pB1, pA1, pB1, ga + k2 + 64, gb + k2 + 64, tid,
                      aoff0, aoff1, boff0, boff1);
  }
  kiter256<false, 0>(acc, pA0, pB0, pA0, pB0, ga, gb, tid,
                     aoff0, aoff1, boff0, boff1);
  kiter256<false, -1>(acc, pA1, pB1, pA1, pB1, ga, gb, tid,
                      aoff0, aoff1, boff0, boff1);

  // ---- epilogue ----
  if (MODE == 1) {
    float* C = (float*)C0;
#pragma unroll
    for (int m = 0; m < 8; ++m) {
      const int rg = row0 + wm * 128 + m * 16 + quad * 4;
#pragma unroll
      for (int n = 0; n < 2; ++n) {
        const int cg = colm + wn * 32 + n * 16 + l15;
#pragma unroll
        for (int r = 0; r < 4; ++r)
          C[(size_t)(rg + r) * 1024 + cg] = acc[m][n][r];
      }
    }
    return;
  }
  if (z == 2) {
    // V -> Vt[(b*16+h)*64+d][t], 8B t-contiguous vector stores
    u16* Vt = (u16*)C2;
#pragma unroll
    for (int m = 0; m < 8; ++m) {
      const int m0 = row0 + wm * 128 + m * 16 + quad * 4;  // token, r=0
      const int bb = m0 >> 11, t = m0 & 2047;
#pragma unroll
      for (int n = 0; n < 2; ++n) {
        const int cg = colm + wn * 32 + n * 16 + l15;      // h*64 + d
        ushort4 w;
        w.x = f32_bf16(acc[m][n][0]);
        w.y = f32_bf16(acc[m][n][1]);
        w.z = f32_bf16(acc[m][n][2]);
        w.w = f32_bf16(acc[m][n][3]);
        *(ushort4*)(Vt + ((size_t)(bb * 16 + (cg >> 6)) * 64 + (cg & 63)) * 2048 + t) = w;
      }
    }
  } else {
    u16* C = (z == 0) ? (u16*)C0 : (u16*)C1;
    const float scale = (z == 0) ? qscale : 1.0f;
#pragma unroll
    for (int m = 0; m < 8; ++m) {
      const int rg = row0 + wm * 128 + m * 16 + quad * 4;
#pragma unroll
      for (int n = 0; n < 2; ++n) {
        const int cg = colm + wn * 32 + n * 16 + l15;
#pragma unroll
        for (int r = 0; r < 4; ++r)
          C[(size_t)(rg + r) * 1024 + cg] = f32_bf16(acc[m][n][r] * scale);
      }
    }
  }
}

// ---------------------------------------------------------------------------
// Flash attention, causal. Q-tile 128 (4 waves x 32 q), 32-key tiles,
// ring-3 K/V LDS buffers, vmcnt(2)+s_barrier (prefetch stays in flight).
// Max-free softmax (m==0, Q pre-scaled by log2e/8), PV one tile behind QK.
// Balanced CU mapping (4 co-resident blocks/CU sum to constant causal work).
// Ks rows: slot = chunk ^ (row&7).  Vs rows: slot = chunk ^ ((row>>1)&3).
// ---------------------------------------------------------------------------
__global__ __launch_bounds__(256, 4) void attn_kernel(
    const u16* __restrict__ Qb, const u16* __restrict__ Kb,
    const u16* __restrict__ Vt, u16* __restrict__ Ob, int T) {
  __shared__ u16 Ks[3][32 * 64];   // ring: [key][feat-slot]
  __shared__ u16 Vs[3][64 * 32];   // ring: [d][key-slot]
  __shared__ u16 Ps[4][32 * 40];   // per-wave P^T: [q][key], stride 40

  // balanced (qblk, bh) decode
  const int ord = blockIdx.x;
  const int i4 = ord & 255, j4 = ord >> 8;
  const int qh = i4 & 15;
  const int base = (j4 & 2) ? (qh ^ 8) : qh;
  const int qblk = (j4 & 1) ? 15 - base : base;
  const int bh = (i4 >> 4) + 16 * j4;

  const int b = bh >> 4, h = bh & 15;
  const int tid = threadIdx.x, lane = tid & 63, wid = tid >> 6;
  const int quad = lane >> 4, l15 = lane & 15;
  const int qb0 = qblk * 128;
  const int D = 1024;
  const int sw = l15 & 7;          // K-row swizzle key
  const int swv = (l15 >> 1) & 3;  // V-row swizzle key

  // Q fragments (B-operand: n=l15 -> q, k=quad*8+j -> feat), 2 q-subtiles
  bf16x8 qf[2][2];
#pragma unroll
  for (int qs = 0; qs < 2; ++qs) {
    const int q = qb0 + wid * 32 + qs * 16 + l15;
    const u16* qp = Qb + ((size_t)b * T + q) * D + h * 64 + quad * 8;
    qf[qs][0] = *(const bf16x8*)(qp);
    qf[qs][1] = *(const bf16x8*)(qp + 32);
  }

  const f32x4 zero = {0.f, 0.f, 0.f, 0.f};
  f32x4 o[2][4];  // [q-subtile][d-subtile]
#pragma unroll
  for (int ms = 0; ms < 2; ++ms)
    for (int nt = 0; nt < 4; ++nt) o[ms][nt] = zero;
  float l_acc[2] = {0.f, 0.f};

  // pipelined PV fragments (held across one tile)
  bf16x8 vf_h[4];
  bf16x8 pf_h[2];

  // staging source addresses with XOR chunk swizzle
  const int krow = tid >> 3, kslot = tid & 7;
  const u16* kg = Kb + ((size_t)b * T + krow) * D + h * 64 + (kslot ^ (krow & 7)) * 8;
  const int vrow = tid >> 2, vslot = tid & 3;
  const u16* vg = Vt + ((size_t)bh * 64 + vrow) * T + (vslot ^ ((vrow >> 1) & 3)) * 8;

  const int ntiles = 4 * (qblk + 1);  // 32-key tiles, >= 4

  // prefetch tiles 0 and 1 (2 loads each)
  gload_lds16(kg, &Ks[0][tid * 8]);
  gload_lds16(vg, &Vs[0][tid * 8]);
  gload_lds16(kg + (size_t)32 * D, &Ks[1][tid * 8]);
  gload_lds16(vg + 32, &Vs[1][tid * 8]);
  barrier_vm2();  // tile-0 data landed; tile-1 loads may stay in flight

  int c = 0;  // ring index t % 3
  for (int t = 0; t < ntiles; ++t) {
    // prefetch tile t+2 (clamped dummy at the tail keeps vmcnt uniform)
    {
      int pb = c + 2; if (pb >= 3) pb -= 3;
      const int tp = (t + 2 < ntiles) ? t + 2 : ntiles - 1;
      const size_t kv = (size_t)tp * 32;
      gload_lds16(kg + kv * D, &Ks[pb][tid * 8]);
      gload_lds16(vg + kv, &Vs[pb][tid * 8]);
    }
    const int kv0 = t * 32;

    // --- QK(t): S^T[key][q], A = K rows (2 subtiles), B = Q (2 subtiles)
    f32x4 s[2][2];
#pragma unroll
    for (int st = 0; st < 2; ++st) {
      const int row = st * 16 + l15;
      const bf16x8 k0 = *(const bf16x8*)(&Ks[c][row * 64 + ((quad ^ sw) * 8)]);
      const bf16x8 k1 = *(const bf16x8*)(&Ks[c][row * 64 + (((4 + quad) ^ sw) * 8)]);
#pragma unroll
      for (int qs = 0; qs < 2; ++qs) {
        s[st][qs] = mfma16(k0, qf[qs][0], zero);
        s[st][qs] = mfma16(k1, qf[qs][1], s[st][qs]);
      }
    }

    // --- PV(t-1): independent of s(t); overlaps QK in the MFMA pipe
    if (t > 0) {
#pragma unroll
      for (int nt = 0; nt < 4; ++nt)
#pragma unroll
        for (int ms = 0; ms < 2; ++ms)
          o[ms][nt] = mfma16(pf_h[ms], vf_h[nt], o[ms][nt]);
    }

    // --- V(t) fragments into registers (independent of s)
#pragma unroll
    for (int nt = 0; nt < 4; ++nt)
      vf_h[nt] = *(const bf16x8*)(
          &Vs[c][(nt * 16 + l15) * 32 + ((quad ^ swv) * 8)]);

    // --- causal mask: last 4 tiles straddle the q-range [qb0, qb0+128)
    if (t >= ntiles - 4) {
#pragma unroll
      for (int qs = 0; qs < 2; ++qs) {
        const int q = qb0 + wid * 32 + qs * 16 + l15;
#pragma unroll
        for (int st = 0; st < 2; ++st)
#pragma unroll
          for (int r = 0; r < 4; ++r) {
            const int key = kv0 + st * 16 + quad * 4 + r;
            if (key > q) s[st][qs][r] = -INFINITY;
          }
      }
    }

    // --- max-free softmax: p = 2^s (Q pre-scaled by log2e); l per-lane
#pragma unroll
    for (int qs = 0; qs < 2; ++qs) {
      float sum = l_acc[qs];
#pragma unroll
      for (int st = 0; st < 2; ++st)
#pragma unroll
        for (int r = 0; r < 4; ++r) {
          const float p = __builtin_amdgcn_exp2f(s[st][qs][r]);
          s[st][qs][r] = p;
          sum += p;
        }
      l_acc[qs] = sum;
    }

    // --- P^T -> LDS (A-layout for PV), 8B vector stores, stride 40
#pragma unroll
    for (int qs = 0; qs < 2; ++qs)
#pragma unroll
      for (int st = 0; st < 2; ++st) {
        bf16x4 w;
        w[0] = (__bf16)s[st][qs][0];
        w[1] = (__bf16)s[st][qs][1];
        w[2] = (__bf16)s[st][qs][2];
        w[3] = (__bf16)s[st][qs][3];
        *(bf16x4*)(&Ps[wid][(qs * 16 + l15) * 40 + st * 16 + quad * 4]) = w;
      }

    // --- P(t) fragments for next iteration's PV (same-wave DS is in-order)
#pragma unroll
    for (int ms = 0; ms < 2; ++ms)
      pf_h[ms] = *(const bf16x8*)(&Ps[wid][(ms * 16 + l15) * 40 + quad * 8]);

    barrier_vm2();  // t+1 data landed; t+2 loads stay in flight
    ++c; if (c >= 3) c = 0;
  }

  // --- flush PV(last)
#pragma unroll
  for (int nt = 0; nt < 4; ++nt)
#pragma unroll
    for (int ms = 0; ms < 2; ++ms)
      o[ms][nt] = mfma16(pf_h[ms], vf_h[nt], o[ms][nt]);

  // epilogue: reduce l across the 4 quads (once), normalize, store
#pragma unroll
  for (int ms = 0; ms < 2; ++ms) {
    float sum = l_acc[ms];
    sum += __shfl_xor(sum, 16);
    sum += __shfl_xor(sum, 32);
    const float linv = 1.0f / sum;
    float lr[4];
#pragma unroll
    for (int r = 0; r < 4; ++r) lr[r] = __shfl(linv, quad * 4 + r);
#pragma unroll
    for (int r = 0; r < 4; ++r) {
      const int qo = qb0 + wid * 32 + ms * 16 + quad * 4 + r;
      u16* op = Ob + ((size_t)b * T + qo) * D + h * 64 + l15;
#pragma unroll
      for (int nt = 0; nt < 4; ++nt)
        op[nt * 16] = f32_bf16(o[ms][nt][r] * lr[r]);
    }
  }
}

// ---------------------------------------------------------------------------
extern "C" void kernel_launch(void* const* d_in, const int* in_sizes, int n_in,
                              void* d_out, int out_size, void* d_ws, size_t ws_size,
                              hipStream_t stream) {
  const float* x  = (const float*)d_in[0];
  const float* wq = (const float*)d_in[1];
  const float* wk = (const float*)d_in[2];
  const float* wv = (const float*)d_in[3];
  const float* wo = (const float*)d_in[4];

  const int B = 4, T = 2048, D = 1024;
  const int M = B * T;  // 8192

  u16* ws = (u16*)d_ws;
  u16* xb  = ws;                         // M*D
  u16* wqb = xb  + (size_t)M * D;        // D*D (contiguous with xb: fused cast)
  u16* wkb = wqb + (size_t)D * D;
  u16* wvb = wkb + (size_t)D * D;
  u16* wob = wvb + (size_t)D * D;
  u16* Qb  = wob + (size_t)D * D;        // M*D (pre-scaled by log2e/8)
  u16* Kb  = Qb  + (size_t)M * D;
  u16* Vt  = Kb  + (size_t)M * D;        // transposed V: [bh][d][t] (from GEMM)
  u16* Ob  = Vt  + (size_t)M * D;        // attention output

  // fused cast (dst regions xb..wob are contiguous)
  const int n_x = M * D / 4, n_w = D * D / 4;
  const int n_tot = n_x + 4 * n_w;
  cvt_all_kernel<<<(n_tot + 255) / 256, 256, 0, stream>>>(x, wq, wk, wv, wo,
                                                          xb, n_x, n_w);

  // fused QKV projection: 32 row-tiles x 24 col-tiles = 768 blocks
  // (3 exact rounds of 256 CUs); Q scaled by (1/sqrt(Dh)) * log2(e)
  gemm256<0><<<768, 512, 0, stream>>>(
      xb, wqb, wkb, wvb, Qb, Kb, Vt, 0.125f * 1.44269504f);

  // flash attention (balanced 1-D grid: 16 q-tiles x 64 bh = 1024 blocks)
  attn_kernel<<<dim3(1024), 256, 0, stream>>>(Qb, Kb, Vt, Ob, T);

  // output projection -> fp32 d_out: 32 x 8 = 256 blocks (1 exact round)
  gemm256<1><<<256, 512, 0, stream>>>(
      Ob, wob, wob, wob, d_out, d_out, d_out, 1.0f);
}